// Round 5
// baseline (702.590 us; speedup 1.0000x reference)
//
#include <hip/hip_runtime.h>
#include <hip/hip_bf16.h>

// Problem constants
#define NQ 8
#define K  1024
#define D  128
#define BB 16
#define T  2048
#define N  (BB*T)          // 32768 rows
#define BR 64              // rows per block
#define NBLK (N/BR)        // 512 blocks -> 2 blocks/CU
#define NW 8               // waves per block (512 threads)
#define WCODES (K/NW)      // 128 codes per wave
#define WTILES (WCODES/16) // 8 col-tiles per wave

// d_out layout (floats): z_q (B,D,T) | indices (B,NQ,T) | commit | util
#define ZQ_SIZE   ((size_t)BB*D*T)
#define IDX_SIZE  ((size_t)BB*NQ*T)
#define SCALAR_OFF (ZQ_SIZE + IDX_SIZE)

// d_ws layout (floats): partials[NBLK] | flags[NQ*K] | norms[NQ*K] | emb16 (NQ*K*D ushorts)
#define WS_PARTIALS 0
#define WS_FLAGS    NBLK
#define WS_NORMS    (NBLK + NQ*K)
#define WS_EMB16_F  (WS_NORMS + NQ*K)
#define WS_REQ_BYTES ((size_t)WS_EMB16_F*4 + (size_t)NQ*K*D*2)

#define EPS  6.0f          // > 2*delta_max of bf16 screen (worst-case ~1.4)
#define CCAP 768

typedef __attribute__((ext_vector_type(8))) short bf16x8;
typedef __attribute__((ext_vector_type(4))) float f32x4;
typedef __attribute__((ext_vector_type(4))) unsigned int u32x4;

__device__ __forceinline__ unsigned short f2bf(float f) {
    unsigned u = __float_as_uint(f);
    u += 0x7FFFu + ((u >> 16) & 1u);   // round-to-nearest-even
    return (unsigned short)(u >> 16);
}

__device__ __forceinline__ unsigned cvt_pk_bf16(float lo, float hi) {
    unsigned r;
    asm("v_cvt_pk_bf16_f32 %0, %1, %2" : "=v"(r) : "v"(lo), "v"(hi));
    return r;   // low16 = bf16(lo), high16 = bf16(hi)
}

__global__ void rvq_norms_kernel(const float* __restrict__ embed,
                                 float* __restrict__ norms) {
    int c = blockIdx.x * blockDim.x + threadIdx.x;
    if (c >= NQ * K) return;
    const float4* e = reinterpret_cast<const float4*>(embed + (size_t)c * D);
    float s = 0.f;
    #pragma unroll 8
    for (int i = 0; i < D / 4; ++i) {
        float4 v = e[i];
        s = fmaf(v.x, v.x, s);
        s = fmaf(v.y, v.y, s);
        s = fmaf(v.z, v.z, s);
        s = fmaf(v.w, v.w, s);
    }
    norms[c] = s;
}

__global__ void rvq_emb16_kernel(const float* __restrict__ embed,
                                 unsigned short* __restrict__ emb16) {
    int gid = blockIdx.x * blockDim.x + threadIdx.x;   // one per 8 elements
    if (gid >= NQ * K * D / 8) return;
    const float4* src = reinterpret_cast<const float4*>(embed) + (size_t)gid * 2;
    float4 a = src[0], b = src[1];
    bf16x8 o;
    o[0] = (short)f2bf(a.x); o[1] = (short)f2bf(a.y);
    o[2] = (short)f2bf(a.z); o[3] = (short)f2bf(a.w);
    o[4] = (short)f2bf(b.x); o[5] = (short)f2bf(b.y);
    o[6] = (short)f2bf(b.z); o[7] = (short)f2bf(b.w);
    reinterpret_cast<bf16x8*>(emb16)[gid] = o;
}

// One sweep over this wave's 128 codes (8 col-tiles of 16). PUSH=0:
// accumulate per-slot min into rmth. PUSH=1: rmth holds thresholds; push.
template<int PUSH>
__device__ __forceinline__ void rvq_score_pass(
    const bf16x8 (&afr)[4][4], const float (&nrm_reg)[WTILES], float (&rmth)[16],
    const unsigned short* __restrict__ e16s, const float* __restrict__ es,
    int use16, int wbase, int lrow, int lkg,
    unsigned int* cand, int* cand_cnt)
{
    #pragma unroll 2
    for (int ct = 0; ct < WTILES; ++ct) {
        const int col = wbase + ct * 16 + lrow;
        bf16x8 bq[4];
        if (use16) {
            const bf16x8* bp = reinterpret_cast<const bf16x8*>(
                e16s + (size_t)col * D + lkg * 8);
            #pragma unroll
            for (int kt = 0; kt < 4; ++kt) bq[kt] = bp[kt * 4];
        } else {
            const float4* fp = reinterpret_cast<const float4*>(
                es + (size_t)col * D + lkg * 8);
            #pragma unroll
            for (int kt = 0; kt < 4; ++kt) {
                float4 u = fp[kt * 8], v = fp[kt * 8 + 1];
                u32x4 w;
                w[0] = cvt_pk_bf16(u.x, u.y); w[1] = cvt_pk_bf16(u.z, u.w);
                w[2] = cvt_pk_bf16(v.x, v.y); w[3] = cvt_pk_bf16(v.z, v.w);
                bq[kt] = __builtin_bit_cast(bf16x8, w);
            }
        }
        f32x4 acc[4];
        #pragma unroll
        for (int rt = 0; rt < 4; ++rt) acc[rt] = (f32x4){0.f, 0.f, 0.f, 0.f};
        #pragma unroll
        for (int kt = 0; kt < 4; ++kt)
            #pragma unroll
            for (int rt = 0; rt < 4; ++rt)
                acc[rt] = __builtin_amdgcn_mfma_f32_16x16x32_bf16(
                    afr[rt][kt], bq[kt], acc[rt], 0, 0, 0);
        const float nrm = nrm_reg[ct];
        #pragma unroll
        for (int rt = 0; rt < 4; ++rt)
            #pragma unroll
            for (int j = 0; j < 4; ++j) {
                float sc = fmaf(-2.f, acc[rt][j], nrm);
                if (PUSH) {
                    if (sc <= rmth[rt * 4 + j]) {
                        int row = rt * 16 + lkg * 4 + j;
                        int pos = atomicAdd(cand_cnt, 1);
                        if (pos < CCAP) cand[pos] = (unsigned)((row << 10) | col);
                    }
                } else {
                    rmth[rt * 4 + j] = fminf(rmth[rt * 4 + j], sc);
                }
            }
    }
}

__global__ __launch_bounds__(512, 4)
void rvq_main_kernel(const float* __restrict__ z_e,
                     const float* __restrict__ embed,
                     const float* __restrict__ ws_norms,
                     const unsigned short* __restrict__ emb16,
                     int use16,
                     float* __restrict__ out,
                     float* __restrict__ ws) {
    __shared__ __align__(16) float res_row[BR][132];   // residual f32, padded rows
    __shared__ unsigned int cand[CCAP];
    __shared__ float row_minw[NW][BR];
    __shared__ unsigned long long row_best[BR];
    __shared__ float cred[512];
    __shared__ int cand_cnt;

    const int tid  = threadIdx.x;
    const int lane = tid & 63;
    const int wave = tid >> 6;           // 0..7, owns codes [wave*128, +128)
    const int blk  = blockIdx.x;
    const int b    = blk >> 5;           // 32 blocks per batch element
    const int t0   = (blk & 31) * BR;

    // ---- initial residual: res_row[r][d] = z_e[b, d, t0+r] (coalesced in r)
    {
        const int r  = tid & 63;
        const int d0 = tid >> 6;         // 0..7
        for (int d = d0; d < D; d += 8)
            res_row[r][d] = z_e[((size_t)b * D + d) * T + t0 + r];
    }
    __syncthreads();

    float commit_acc = 0.f;
    const int lrow  = lane & 15;
    const int lkg   = lane >> 4;
    const int wbase = wave * WCODES;

    for (int s = 0; s < NQ; ++s) {
        const float* es = embed + (size_t)s * K * D;
        const float* ns = ws_norms + (size_t)s * K;
        const unsigned short* e16s = emb16 + (size_t)s * K * D;

        // per-stage resets (visible after barrier (1))
        if (tid < BR) row_best[tid] = ~0ULL;
        if (tid == 0) cand_cnt = 0;

        // stage norms for this thread's columns
        float nrm_reg[WTILES];
        #pragma unroll
        for (int ct = 0; ct < WTILES; ++ct) nrm_reg[ct] = ns[wbase + ct * 16 + lrow];

        // ---- A fragments from residual (packed bf16 convert)
        bf16x8 afr[4][4];
        #pragma unroll
        for (int rt = 0; rt < 4; ++rt) {
            const float* rp = &res_row[rt * 16 + lrow][lkg * 8];
            #pragma unroll
            for (int kt = 0; kt < 4; ++kt) {
                float4 u = *reinterpret_cast<const float4*>(rp + kt * 32);
                float4 v = *reinterpret_cast<const float4*>(rp + kt * 32 + 4);
                u32x4 w;
                w[0] = cvt_pk_bf16(u.x, u.y); w[1] = cvt_pk_bf16(u.z, u.w);
                w[2] = cvt_pk_bf16(v.x, v.y); w[3] = cvt_pk_bf16(v.z, v.w);
                afr[rt][kt] = __builtin_bit_cast(bf16x8, w);
            }
        }

        float rmth[16];
        #pragma unroll
        for (int i = 0; i < 16; ++i) rmth[i] = 3.4e38f;

        // ---- pass 1: per-slot min only
        rvq_score_pass<0>(afr, nrm_reg, rmth, e16s, es, use16,
                          wbase, lrow, lkg, cand, &cand_cnt);

        // one butterfly at the end (16 col lanes -> wave row min)
        #pragma unroll
        for (int i = 0; i < 16; ++i) {
            float m = rmth[i];
            m = fminf(m, __shfl_xor(m, 1, 16));
            m = fminf(m, __shfl_xor(m, 2, 16));
            m = fminf(m, __shfl_xor(m, 4, 16));
            m = fminf(m, __shfl_xor(m, 8, 16));
            rmth[i] = m;
        }
        if (lrow == 0) {
            #pragma unroll
            for (int i = 0; i < 16; ++i)
                row_minw[wave][(i >> 2) * 16 + lkg * 4 + (i & 3)] = rmth[i];
        }
        __syncthreads();   // (1) row_minw + resets visible

        // thresholds = global row min over 8 waves + EPS
        #pragma unroll
        for (int i = 0; i < 16; ++i) {
            int row = (i >> 2) * 16 + lkg * 4 + (i & 3);
            float m = fminf(fminf(fminf(row_minw[0][row], row_minw[1][row]),
                                  fminf(row_minw[2][row], row_minw[3][row])),
                            fminf(fminf(row_minw[4][row], row_minw[5][row]),
                                  fminf(row_minw[6][row], row_minw[7][row])));
            rmth[i] = m + EPS;
        }

        // ---- pass 2: recompute scores, push rare candidates
        rvq_score_pass<1>(afr, nrm_reg, rmth, e16s, es, use16,
                          wbase, lrow, lkg, cand, &cand_cnt);
        __syncthreads();   // (2) cand ready

        // ---- exact f32 rescore; lexicographic (dist, idx) min
        int nc = cand_cnt; if (nc > CCAP) nc = CCAP;
        for (int i = tid; i < nc; i += 512) {
            unsigned e = cand[i];
            int row = (int)(e >> 10), col = (int)(e & (K - 1));
            const float*  rp = &res_row[row][0];
            const float4* ep = reinterpret_cast<const float4*>(es + (size_t)col * D);
            float dot = 0.f;
            #pragma unroll 8
            for (int q = 0; q < 32; ++q) {
                float4 rv = *reinterpret_cast<const float4*>(rp + q * 4);
                float4 evv = ep[q];
                dot = fmaf(rv.x, evv.x, dot);
                dot = fmaf(rv.y, evv.y, dot);
                dot = fmaf(rv.z, evv.z, dot);
                dot = fmaf(rv.w, evv.w, dot);
            }
            float dist = fmaf(-2.f, dot, ns[col]);
            unsigned du = __float_as_uint(dist);
            du ^= (du >> 31) ? 0xFFFFFFFFu : 0x80000000u;
            unsigned long long key = ((unsigned long long)du << 32) | (unsigned)col;
            atomicMin(&row_best[row], key);
        }
        __syncthreads();   // (3) row_best final

        // ---- index out + flags + residual update
        if (tid < BR) {
            int idx = (int)(row_best[tid] & (unsigned)(K - 1));
            out[ZQ_SIZE + ((size_t)b * NQ + s) * T + t0 + tid] = (float)idx;
            ws[WS_FLAGS + s * K + idx] = 1.0f;   // benign race
        }
        {
            const int row = tid >> 3;            // 0..63
            const int d0  = (tid & 7) * 16;      // 16 floats per thread
            const int idx = (int)(row_best[row] & (unsigned)(K - 1));
            const float* ev = es + (size_t)idx * D + d0;
            float* rr = &res_row[row][d0];
            #pragma unroll
            for (int p = 0; p < 4; ++p) {
                float4 e4 = *reinterpret_cast<const float4*>(ev + p * 4);
                float4 r4 = *reinterpret_cast<float4*>(rr + p * 4);
                float tx = e4.x - r4.x, zx = r4.x + tx;
                float ty = e4.y - r4.y, zy = r4.y + ty;
                float tz = e4.z - r4.z, zz = r4.z + tz;
                float tw = e4.w - r4.w, zw = r4.w + tw;
                float4 nr;
                nr.x = r4.x - zx; nr.y = r4.y - zy; nr.z = r4.z - zz; nr.w = r4.w - zw;
                commit_acc = fmaf(tx, tx, commit_acc);
                commit_acc = fmaf(ty, ty, commit_acc);
                commit_acc = fmaf(tz, tz, commit_acc);
                commit_acc = fmaf(tw, tw, commit_acc);
                *reinterpret_cast<float4*>(rr + p * 4) = nr;
            }
        }
        __syncthreads();   // (4) res_row stable, row_best reads done
    }

    // ---- z_q = z_e - final residual (telescoped sum of stage z_q_st)
    {
        const int r  = tid & 63;
        const int d0 = tid >> 6;
        for (int d = d0; d < D; d += 8) {
            size_t gi = ((size_t)b * D + d) * T + t0 + r;
            out[gi] = z_e[gi] - res_row[r][d];
        }
    }

    // ---- deterministic block reduction of commit partials
    cred[tid] = commit_acc;
    __syncthreads();
    for (int o = 256; o > 0; o >>= 1) {
        if (tid < o) cred[tid] += cred[tid + o];
        __syncthreads();
    }
    if (tid == 0) ws[WS_PARTIALS + blk] = cred[0];
}

__global__ void rvq_finalize_kernel(const float* __restrict__ ws,
                                    float* __restrict__ out) {
    __shared__ float sbuf[256];
    const int tid = threadIdx.x;

    float cs = 0.f;
    for (int i = tid; i < NBLK; i += 256) cs += ws[WS_PARTIALS + i];
    sbuf[tid] = cs;
    __syncthreads();
    for (int o = 128; o > 0; o >>= 1) {
        if (tid < o) sbuf[tid] += sbuf[tid + o];
        __syncthreads();
    }
    float commit = sbuf[0] / ((float)NQ * (float)N * (float)D);
    __syncthreads();

    float fs = 0.f;
    for (int i = tid; i < NQ * K; i += 256)
        fs += (ws[WS_FLAGS + i] != 0.f) ? 1.f : 0.f;
    sbuf[tid] = fs;
    __syncthreads();
    for (int o = 128; o > 0; o >>= 1) {
        if (tid < o) sbuf[tid] += sbuf[tid + o];
        __syncthreads();
    }
    if (tid == 0) {
        out[SCALAR_OFF + 0] = commit;
        out[SCALAR_OFF + 1] = sbuf[0] / (float)(NQ * K);
    }
}

extern "C" void kernel_launch(void* const* d_in, const int* in_sizes, int n_in,
                              void* d_out, int out_size, void* d_ws, size_t ws_size,
                              hipStream_t stream) {
    const float* z_e   = (const float*)d_in[0];
    const float* embed = (const float*)d_in[1];
    float* out = (float*)d_out;
    float* ws  = (float*)d_ws;

    int use16 = (ws_size >= WS_REQ_BYTES) ? 1 : 0;

    hipMemsetAsync(d_ws, 0, (NBLK + NQ * K) * sizeof(float), stream);
    rvq_norms_kernel<<<(NQ * K + 255) / 256, 256, 0, stream>>>(embed, ws + WS_NORMS);
    if (use16)
        rvq_emb16_kernel<<<(NQ * K * D / 8 + 255) / 256, 256, 0, stream>>>(
            embed, (unsigned short*)(ws + WS_EMB16_F));
    rvq_main_kernel<<<NBLK, 512, 0, stream>>>(
        z_e, embed, ws + WS_NORMS, (const unsigned short*)(ws + WS_EMB16_F),
        use16, out, ws);
    rvq_finalize_kernel<<<1, 256, 0, stream>>>(ws, out);
}

// Round 6
// 596.706 us; speedup vs baseline: 1.1774x; 1.1774x over previous
//
#include <hip/hip_runtime.h>
#include <hip/hip_bf16.h>

// Problem constants
#define NQ 8
#define K  1024
#define D  128
#define BB 16
#define T  2048
#define N  (BB*T)          // 32768 rows
#define BR 64              // rows per block
#define NBLK (N/BR)        // 512 blocks -> 2 blocks/CU
#define WT 16              // col-tiles per wave (256 codes)

// d_out layout (floats): z_q (B,D,T) | indices (B,NQ,T) | commit | util
#define ZQ_SIZE   ((size_t)BB*D*T)
#define IDX_SIZE  ((size_t)BB*NQ*T)
#define SCALAR_OFF (ZQ_SIZE + IDX_SIZE)

// d_ws layout (floats): partials[NBLK] | flags[NQ*K] | norms[NQ*K] | emb16 (NQ*K*D ushorts)
#define WS_PARTIALS 0
#define WS_FLAGS    NBLK
#define WS_NORMS    (NBLK + NQ*K)
#define WS_EMB16_F  (WS_NORMS + NQ*K)
#define WS_REQ_BYTES ((size_t)WS_EMB16_F*4 + (size_t)NQ*K*D*2)

#define EPS  6.0f          // > 2*delta_max of bf16 screen (worst-case ~2)
#define CCAP 768

typedef __attribute__((ext_vector_type(8))) short bf16x8;
typedef __attribute__((ext_vector_type(4))) float f32x4;
typedef __attribute__((ext_vector_type(4))) unsigned int u32x4;

__device__ __forceinline__ unsigned short f2bf(float f) {
    unsigned u = __float_as_uint(f);
    u += 0x7FFFu + ((u >> 16) & 1u);   // round-to-nearest-even
    return (unsigned short)(u >> 16);
}

__device__ __forceinline__ unsigned cvt_pk_bf16(float lo, float hi) {
    unsigned r;
    asm("v_cvt_pk_bf16_f32 %0, %1, %2" : "=v"(r) : "v"(lo), "v"(hi));
    return r;   // low16 = bf16(lo), high16 = bf16(hi)
}

__global__ void rvq_norms_kernel(const float* __restrict__ embed,
                                 float* __restrict__ norms) {
    int c = blockIdx.x * blockDim.x + threadIdx.x;
    if (c >= NQ * K) return;
    const float4* e = reinterpret_cast<const float4*>(embed + (size_t)c * D);
    float s = 0.f;
    #pragma unroll 8
    for (int i = 0; i < D / 4; ++i) {
        float4 v = e[i];
        s = fmaf(v.x, v.x, s);
        s = fmaf(v.y, v.y, s);
        s = fmaf(v.z, v.z, s);
        s = fmaf(v.w, v.w, s);
    }
    norms[c] = s;
}

__global__ void rvq_emb16_kernel(const float* __restrict__ embed,
                                 unsigned short* __restrict__ emb16) {
    int gid = blockIdx.x * blockDim.x + threadIdx.x;   // one per 8 elements
    if (gid >= NQ * K * D / 8) return;
    const float4* src = reinterpret_cast<const float4*>(embed) + (size_t)gid * 2;
    float4 a = src[0], b = src[1];
    bf16x8 o;
    o[0] = (short)f2bf(a.x); o[1] = (short)f2bf(a.y);
    o[2] = (short)f2bf(a.z); o[3] = (short)f2bf(a.w);
    o[4] = (short)f2bf(b.x); o[5] = (short)f2bf(b.y);
    o[6] = (short)f2bf(b.z); o[7] = (short)f2bf(b.w);
    reinterpret_cast<bf16x8*>(emb16)[gid] = o;
}

__device__ __forceinline__ void load_bq(bf16x8 (&bq)[4],
                                        const unsigned short* __restrict__ e16s,
                                        const float* __restrict__ es,
                                        int use16, int col, int lkg) {
    if (use16) {
        const bf16x8* bp = reinterpret_cast<const bf16x8*>(
            e16s + (size_t)col * D + lkg * 8);
        #pragma unroll
        for (int kt = 0; kt < 4; ++kt) bq[kt] = bp[kt * 4];
    } else {
        const float4* fp = reinterpret_cast<const float4*>(
            es + (size_t)col * D + lkg * 8);
        #pragma unroll
        for (int kt = 0; kt < 4; ++kt) {
            float4 u = fp[kt * 8], v = fp[kt * 8 + 1];
            u32x4 w;
            w[0] = cvt_pk_bf16(u.x, u.y); w[1] = cvt_pk_bf16(u.z, u.w);
            w[2] = cvt_pk_bf16(v.x, v.y); w[3] = cvt_pk_bf16(v.z, v.w);
            bq[kt] = __builtin_bit_cast(bf16x8, w);
        }
    }
}

// One sweep over this wave's 256 codes (16 col-tiles of 16), with explicit
// depth-1 B prefetch. PUSH=0: accumulate per-slot min into rmth. PUSH=1:
// rmth holds thresholds; push candidates within threshold.
template<int PUSH>
__device__ __forceinline__ void rvq_score_pass(
    const bf16x8 (&afr)[4][4], const float (&nrm_reg)[WT], float (&rmth)[16],
    const unsigned short* __restrict__ e16s, const float* __restrict__ es,
    int use16, int wbase, int lrow, int lkg,
    unsigned int* cand, int* cand_cnt)
{
    bf16x8 bq[2][4];
    load_bq(bq[0], e16s, es, use16, wbase + lrow, lkg);
    #pragma unroll
    for (int ct = 0; ct < WT; ++ct) {
        const int cur = ct & 1, nxt = cur ^ 1;   // compile-time (full unroll)
        if (ct + 1 < WT)
            load_bq(bq[nxt], e16s, es, use16, wbase + (ct + 1) * 16 + lrow, lkg);
        f32x4 acc[4];
        #pragma unroll
        for (int rt = 0; rt < 4; ++rt) acc[rt] = (f32x4){0.f, 0.f, 0.f, 0.f};
        #pragma unroll
        for (int kt = 0; kt < 4; ++kt)
            #pragma unroll
            for (int rt = 0; rt < 4; ++rt)
                acc[rt] = __builtin_amdgcn_mfma_f32_16x16x32_bf16(
                    afr[rt][kt], bq[cur][kt], acc[rt], 0, 0, 0);
        const float nrm = nrm_reg[ct];
        const int col = wbase + ct * 16 + lrow;
        #pragma unroll
        for (int rt = 0; rt < 4; ++rt)
            #pragma unroll
            for (int j = 0; j < 4; ++j) {
                float sc = fmaf(-2.f, acc[rt][j], nrm);
                if (PUSH) {
                    if (sc <= rmth[rt * 4 + j]) {
                        int row = rt * 16 + lkg * 4 + j;
                        int pos = atomicAdd(cand_cnt, 1);
                        if (pos < CCAP) cand[pos] = (unsigned)((row << 10) | col);
                    }
                } else {
                    rmth[rt * 4 + j] = fminf(rmth[rt * 4 + j], sc);
                }
            }
    }
}

__global__ __launch_bounds__(256, 2)
void rvq_main_kernel(const float* __restrict__ z_e,
                     const float* __restrict__ embed,
                     const float* __restrict__ ws_norms,
                     const unsigned short* __restrict__ emb16,
                     int use16,
                     float* __restrict__ out,
                     float* __restrict__ ws) {
    __shared__ __align__(16) float res_row[BR][132];   // residual f32, padded rows
    __shared__ unsigned int cand[CCAP];
    __shared__ float row_minw[4][BR];
    __shared__ unsigned long long row_best[BR];
    __shared__ float cred[256];
    __shared__ int cand_cnt;

    const int tid  = threadIdx.x;
    const int lane = tid & 63;
    const int wave = tid >> 6;           // owns codes [wave*256, wave*256+256)
    const int blk  = blockIdx.x;
    const int b    = blk >> 5;
    const int t0   = (blk & 31) * BR;

    // ---- initial residual: res_row[r][d] = z_e[b, d, t0+r] (coalesced in r)
    {
        const int r  = tid & 63;
        const int d0 = tid >> 6;
        for (int d = d0; d < D; d += 4)
            res_row[r][d] = z_e[((size_t)b * D + d) * T + t0 + r];
    }
    __syncthreads();

    float commit_acc = 0.f;
    const int lrow  = lane & 15;
    const int lkg   = lane >> 4;
    const int wbase = wave * 256;

    for (int s = 0; s < NQ; ++s) {
        const float* es = embed + (size_t)s * K * D;
        const float* ns = ws_norms + (size_t)s * K;
        const unsigned short* e16s = emb16 + (size_t)s * K * D;

        // per-stage resets (visible after barrier (1))
        if (tid < BR) row_best[tid] = ~0ULL;
        if (tid == 0) cand_cnt = 0;

        // stage norms for this thread's 16 columns
        float nrm_reg[WT];
        #pragma unroll
        for (int ct = 0; ct < WT; ++ct) nrm_reg[ct] = ns[wbase + ct * 16 + lrow];

        // ---- A fragments from residual (packed bf16 convert)
        bf16x8 afr[4][4];
        #pragma unroll
        for (int rt = 0; rt < 4; ++rt) {
            const float* rp = &res_row[rt * 16 + lrow][lkg * 8];
            #pragma unroll
            for (int kt = 0; kt < 4; ++kt) {
                float4 u = *reinterpret_cast<const float4*>(rp + kt * 32);
                float4 v = *reinterpret_cast<const float4*>(rp + kt * 32 + 4);
                u32x4 w;
                w[0] = cvt_pk_bf16(u.x, u.y); w[1] = cvt_pk_bf16(u.z, u.w);
                w[2] = cvt_pk_bf16(v.x, v.y); w[3] = cvt_pk_bf16(v.z, v.w);
                afr[rt][kt] = __builtin_bit_cast(bf16x8, w);
            }
        }

        float rmth[16];
        #pragma unroll
        for (int i = 0; i < 16; ++i) rmth[i] = 3.4e38f;

        // ---- pass 1: per-slot min only
        rvq_score_pass<0>(afr, nrm_reg, rmth, e16s, es, use16,
                          wbase, lrow, lkg, cand, &cand_cnt);

        // one butterfly at the end (16 col lanes -> wave row min)
        #pragma unroll
        for (int i = 0; i < 16; ++i) {
            float m = rmth[i];
            m = fminf(m, __shfl_xor(m, 1, 16));
            m = fminf(m, __shfl_xor(m, 2, 16));
            m = fminf(m, __shfl_xor(m, 4, 16));
            m = fminf(m, __shfl_xor(m, 8, 16));
            rmth[i] = m;
        }
        if (lrow == 0) {
            #pragma unroll
            for (int i = 0; i < 16; ++i)
                row_minw[wave][(i >> 2) * 16 + lkg * 4 + (i & 3)] = rmth[i];
        }
        __syncthreads();   // (1) row_minw + resets visible

        // thresholds = global row min over 4 waves + EPS
        #pragma unroll
        for (int i = 0; i < 16; ++i) {
            int row = (i >> 2) * 16 + lkg * 4 + (i & 3);
            float m = fminf(fminf(row_minw[0][row], row_minw[1][row]),
                            fminf(row_minw[2][row], row_minw[3][row]));
            rmth[i] = m + EPS;
        }

        // ---- pass 2: recompute scores, push rare candidates
        rvq_score_pass<1>(afr, nrm_reg, rmth, e16s, es, use16,
                          wbase, lrow, lkg, cand, &cand_cnt);
        __syncthreads();   // (2) cand ready

        // ---- exact f32 rescore; 4 independent FMA chains; lex (dist,idx) min
        int nc = cand_cnt; if (nc > CCAP) nc = CCAP;
        for (int i = tid; i < nc; i += 256) {
            unsigned e = cand[i];
            int row = (int)(e >> 10), col = (int)(e & (K - 1));
            const float*  rp = &res_row[row][0];
            const float4* ep = reinterpret_cast<const float4*>(es + (size_t)col * D);
            float d0 = 0.f, d1 = 0.f, d2 = 0.f, d3 = 0.f;
            #pragma unroll
            for (int q = 0; q < 8; ++q) {
                float4 rv0 = *reinterpret_cast<const float4*>(rp + q * 16);
                float4 rv1 = *reinterpret_cast<const float4*>(rp + q * 16 + 4);
                float4 rv2 = *reinterpret_cast<const float4*>(rp + q * 16 + 8);
                float4 rv3 = *reinterpret_cast<const float4*>(rp + q * 16 + 12);
                float4 e0 = ep[q * 4], e1 = ep[q * 4 + 1];
                float4 e2 = ep[q * 4 + 2], e3 = ep[q * 4 + 3];
                d0 = fmaf(rv0.x, e0.x, d0); d0 = fmaf(rv0.y, e0.y, d0);
                d0 = fmaf(rv0.z, e0.z, d0); d0 = fmaf(rv0.w, e0.w, d0);
                d1 = fmaf(rv1.x, e1.x, d1); d1 = fmaf(rv1.y, e1.y, d1);
                d1 = fmaf(rv1.z, e1.z, d1); d1 = fmaf(rv1.w, e1.w, d1);
                d2 = fmaf(rv2.x, e2.x, d2); d2 = fmaf(rv2.y, e2.y, d2);
                d2 = fmaf(rv2.z, e2.z, d2); d2 = fmaf(rv2.w, e2.w, d2);
                d3 = fmaf(rv3.x, e3.x, d3); d3 = fmaf(rv3.y, e3.y, d3);
                d3 = fmaf(rv3.z, e3.z, d3); d3 = fmaf(rv3.w, e3.w, d3);
            }
            float dot = (d0 + d1) + (d2 + d3);
            float dist = fmaf(-2.f, dot, ns[col]);
            unsigned du = __float_as_uint(dist);
            du ^= (du >> 31) ? 0xFFFFFFFFu : 0x80000000u;
            unsigned long long key = ((unsigned long long)du << 32) | (unsigned)col;
            atomicMin(&row_best[row], key);
        }
        __syncthreads();   // (3) row_best final

        // ---- index out + flags + residual update
        if (tid < BR) {
            int idx = (int)(row_best[tid] & (unsigned)(K - 1));
            out[ZQ_SIZE + ((size_t)b * NQ + s) * T + t0 + tid] = (float)idx;
            ws[WS_FLAGS + s * K + idx] = 1.0f;   // benign race
        }
        {
            const int row = tid >> 2;
            const int d0g = (tid & 3) * 32;
            const int idx = (int)(row_best[row] & (unsigned)(K - 1));
            const float* ev = es + (size_t)idx * D + d0g;
            float* rr = &res_row[row][d0g];
            #pragma unroll
            for (int p = 0; p < 8; ++p) {
                float4 e4 = *reinterpret_cast<const float4*>(ev + p * 4);
                float4 r4 = *reinterpret_cast<float4*>(rr + p * 4);
                float tx = e4.x - r4.x, zx = r4.x + tx;
                float ty = e4.y - r4.y, zy = r4.y + ty;
                float tz = e4.z - r4.z, zz = r4.z + tz;
                float tw = e4.w - r4.w, zw = r4.w + tw;
                float4 nr;
                nr.x = r4.x - zx; nr.y = r4.y - zy; nr.z = r4.z - zz; nr.w = r4.w - zw;
                commit_acc = fmaf(tx, tx, commit_acc);
                commit_acc = fmaf(ty, ty, commit_acc);
                commit_acc = fmaf(tz, tz, commit_acc);
                commit_acc = fmaf(tw, tw, commit_acc);
                *reinterpret_cast<float4*>(rr + p * 4) = nr;
            }
        }
        __syncthreads();   // (4) res_row stable, row_best reads done
    }

    // ---- z_q = z_e - final residual (telescoped sum of stage z_q_st)
    {
        const int r  = tid & 63;
        const int d0 = tid >> 6;
        for (int d = d0; d < D; d += 4) {
            size_t gi = ((size_t)b * D + d) * T + t0 + r;
            out[gi] = z_e[gi] - res_row[r][d];
        }
    }

    // ---- deterministic block reduction of commit partials
    cred[tid] = commit_acc;
    __syncthreads();
    for (int o = 128; o > 0; o >>= 1) {
        if (tid < o) cred[tid] += cred[tid + o];
        __syncthreads();
    }
    if (tid == 0) ws[WS_PARTIALS + blk] = cred[0];
}

__global__ void rvq_finalize_kernel(const float* __restrict__ ws,
                                    float* __restrict__ out) {
    __shared__ float sbuf[256];
    const int tid = threadIdx.x;

    float cs = 0.f;
    for (int i = tid; i < NBLK; i += 256) cs += ws[WS_PARTIALS + i];
    sbuf[tid] = cs;
    __syncthreads();
    for (int o = 128; o > 0; o >>= 1) {
        if (tid < o) sbuf[tid] += sbuf[tid + o];
        __syncthreads();
    }
    float commit = sbuf[0] / ((float)NQ * (float)N * (float)D);
    __syncthreads();

    float fs = 0.f;
    for (int i = tid; i < NQ * K; i += 256)
        fs += (ws[WS_FLAGS + i] != 0.f) ? 1.f : 0.f;
    sbuf[tid] = fs;
    __syncthreads();
    for (int o = 128; o > 0; o >>= 1) {
        if (tid < o) sbuf[tid] += sbuf[tid + o];
        __syncthreads();
    }
    if (tid == 0) {
        out[SCALAR_OFF + 0] = commit;
        out[SCALAR_OFF + 1] = sbuf[0] / (float)(NQ * K);
    }
}

extern "C" void kernel_launch(void* const* d_in, const int* in_sizes, int n_in,
                              void* d_out, int out_size, void* d_ws, size_t ws_size,
                              hipStream_t stream) {
    const float* z_e   = (const float*)d_in[0];
    const float* embed = (const float*)d_in[1];
    float* out = (float*)d_out;
    float* ws  = (float*)d_ws;

    int use16 = (ws_size >= WS_REQ_BYTES) ? 1 : 0;

    hipMemsetAsync(d_ws, 0, (NBLK + NQ * K) * sizeof(float), stream);
    rvq_norms_kernel<<<(NQ * K + 255) / 256, 256, 0, stream>>>(embed, ws + WS_NORMS);
    if (use16)
        rvq_emb16_kernel<<<(NQ * K * D / 8 + 255) / 256, 256, 0, stream>>>(
            embed, (unsigned short*)(ws + WS_EMB16_F));
    rvq_main_kernel<<<NBLK, 256, 0, stream>>>(
        z_e, embed, ws + WS_NORMS, (const unsigned short*)(ws + WS_EMB16_F),
        use16, out, ws);
    rvq_finalize_kernel<<<1, 256, 0, stream>>>(ws, out);
}

// Round 7
// 388.615 us; speedup vs baseline: 1.8079x; 1.5355x over previous
//
#include <hip/hip_runtime.h>
#include <hip/hip_bf16.h>

// Problem constants
#define NQ 8
#define K  1024
#define D  128
#define BB 16
#define T  2048
#define N  (BB*T)          // 32768 rows
#define BR 64              // rows per block
#define NBLK (N/BR)        // 512 blocks -> 2 blocks/CU
#define NW 8               // waves per block (512 threads)
#define WCODES (K/NW)      // 128 codes per wave
#define WTILES (WCODES/16) // 8 col-tiles per wave

// d_out layout (floats): z_q (B,D,T) | indices (B,NQ,T) | commit | util
#define ZQ_SIZE   ((size_t)BB*D*T)
#define IDX_SIZE  ((size_t)BB*NQ*T)
#define SCALAR_OFF (ZQ_SIZE + IDX_SIZE)

// d_ws layout (floats): partials[NBLK] | flags[NQ*K] | norms[NQ*K] | emb16 (NQ*K*D ushorts)
#define WS_PARTIALS 0
#define WS_FLAGS    NBLK
#define WS_NORMS    (NBLK + NQ*K)
#define WS_EMB16_F  (WS_NORMS + NQ*K)
#define WS_REQ_BYTES ((size_t)WS_EMB16_F*4 + (size_t)NQ*K*D*2)

#define EPS  6.0f          // > 2*delta_max of bf16 screen (worst-case ~2)
#define CCAP 768

typedef __attribute__((ext_vector_type(8))) short bf16x8;
typedef __attribute__((ext_vector_type(4))) float f32x4;
typedef __attribute__((ext_vector_type(4))) unsigned int u32x4;

__device__ __forceinline__ unsigned short f2bf(float f) {
    unsigned u = __float_as_uint(f);
    u += 0x7FFFu + ((u >> 16) & 1u);   // round-to-nearest-even
    return (unsigned short)(u >> 16);
}

__device__ __forceinline__ unsigned cvt_pk_bf16(float lo, float hi) {
    unsigned r;
    asm("v_cvt_pk_bf16_f32 %0, %1, %2" : "=v"(r) : "v"(lo), "v"(hi));
    return r;   // low16 = bf16(lo), high16 = bf16(hi)
}

__global__ void rvq_norms_kernel(const float* __restrict__ embed,
                                 float* __restrict__ norms) {
    int c = blockIdx.x * blockDim.x + threadIdx.x;
    if (c >= NQ * K) return;
    const float4* e = reinterpret_cast<const float4*>(embed + (size_t)c * D);
    float s = 0.f;
    #pragma unroll 8
    for (int i = 0; i < D / 4; ++i) {
        float4 v = e[i];
        s = fmaf(v.x, v.x, s);
        s = fmaf(v.y, v.y, s);
        s = fmaf(v.z, v.z, s);
        s = fmaf(v.w, v.w, s);
    }
    norms[c] = s;
}

__global__ void rvq_emb16_kernel(const float* __restrict__ embed,
                                 unsigned short* __restrict__ emb16) {
    int gid = blockIdx.x * blockDim.x + threadIdx.x;   // one per 8 elements
    if (gid >= NQ * K * D / 8) return;
    const float4* src = reinterpret_cast<const float4*>(embed) + (size_t)gid * 2;
    float4 a = src[0], b = src[1];
    bf16x8 o;
    o[0] = (short)f2bf(a.x); o[1] = (short)f2bf(a.y);
    o[2] = (short)f2bf(a.z); o[3] = (short)f2bf(a.w);
    o[4] = (short)f2bf(b.x); o[5] = (short)f2bf(b.y);
    o[6] = (short)f2bf(b.z); o[7] = (short)f2bf(b.w);
    reinterpret_cast<bf16x8*>(emb16)[gid] = o;
}

// One sweep over this wave's 128 codes (8 col-tiles of 16). PUSH=0:
// accumulate per-slot min into rmth. PUSH=1: rmth holds thresholds; push.
template<int PUSH>
__device__ __forceinline__ void rvq_score_pass(
    const bf16x8 (&afr)[4][4], const float (&nrm_reg)[WTILES], float (&rmth)[16],
    const unsigned short* __restrict__ e16s, const float* __restrict__ es,
    int use16, int wbase, int lrow, int lkg,
    unsigned int* cand, int* cand_cnt)
{
    #pragma unroll 2
    for (int ct = 0; ct < WTILES; ++ct) {
        const int col = wbase + ct * 16 + lrow;
        bf16x8 bq[4];
        if (use16) {
            const bf16x8* bp = reinterpret_cast<const bf16x8*>(
                e16s + (size_t)col * D + lkg * 8);
            #pragma unroll
            for (int kt = 0; kt < 4; ++kt) bq[kt] = bp[kt * 4];
        } else {
            const float4* fp = reinterpret_cast<const float4*>(
                es + (size_t)col * D + lkg * 8);
            #pragma unroll
            for (int kt = 0; kt < 4; ++kt) {
                float4 u = fp[kt * 8], v = fp[kt * 8 + 1];
                u32x4 w;
                w[0] = cvt_pk_bf16(u.x, u.y); w[1] = cvt_pk_bf16(u.z, u.w);
                w[2] = cvt_pk_bf16(v.x, v.y); w[3] = cvt_pk_bf16(v.z, v.w);
                bq[kt] = __builtin_bit_cast(bf16x8, w);
            }
        }
        f32x4 acc[4];
        #pragma unroll
        for (int rt = 0; rt < 4; ++rt) acc[rt] = (f32x4){0.f, 0.f, 0.f, 0.f};
        #pragma unroll
        for (int kt = 0; kt < 4; ++kt)
            #pragma unroll
            for (int rt = 0; rt < 4; ++rt)
                acc[rt] = __builtin_amdgcn_mfma_f32_16x16x32_bf16(
                    afr[rt][kt], bq[kt], acc[rt], 0, 0, 0);
        const float nrm = nrm_reg[ct];
        #pragma unroll
        for (int rt = 0; rt < 4; ++rt)
            #pragma unroll
            for (int j = 0; j < 4; ++j) {
                float sc = fmaf(-2.f, acc[rt][j], nrm);
                if (PUSH) {
                    if (sc <= rmth[rt * 4 + j]) {
                        int row = rt * 16 + lkg * 4 + j;
                        int pos = atomicAdd(cand_cnt, 1);
                        if (pos < CCAP) cand[pos] = (unsigned)((row << 10) | col);
                    }
                } else {
                    rmth[rt * 4 + j] = fminf(rmth[rt * 4 + j], sc);
                }
            }
    }
}

__global__ __launch_bounds__(512, 2)
void rvq_main_kernel(const float* __restrict__ z_e,
                     const float* __restrict__ embed,
                     const float* __restrict__ ws_norms,
                     const unsigned short* __restrict__ emb16,
                     int use16,
                     float* __restrict__ out,
                     float* __restrict__ ws) {
    __shared__ __align__(16) float res_row[BR][132];   // residual f32, padded rows
    __shared__ unsigned int cand[CCAP];
    __shared__ float row_minw[NW][BR];
    __shared__ unsigned long long row_best[BR];
    __shared__ float cred[512];
    __shared__ int cand_cnt;

    const int tid  = threadIdx.x;
    const int lane = tid & 63;
    const int wave = tid >> 6;           // 0..7, owns codes [wave*128, +128)
    const int blk  = blockIdx.x;
    const int b    = blk >> 5;           // 32 blocks per batch element
    const int t0   = (blk & 31) * BR;

    // ---- initial residual: res_row[r][d] = z_e[b, d, t0+r] (coalesced in r)
    {
        const int r  = tid & 63;
        const int d0 = tid >> 6;         // 0..7
        for (int d = d0; d < D; d += 8)
            res_row[r][d] = z_e[((size_t)b * D + d) * T + t0 + r];
    }
    __syncthreads();

    float commit_acc = 0.f;
    const int lrow  = lane & 15;
    const int lkg   = lane >> 4;
    const int wbase = wave * WCODES;

    for (int s = 0; s < NQ; ++s) {
        const float* es = embed + (size_t)s * K * D;
        const float* ns = ws_norms + (size_t)s * K;
        const unsigned short* e16s = emb16 + (size_t)s * K * D;

        // per-stage resets (visible after barrier (1))
        if (tid < BR) row_best[tid] = ~0ULL;
        if (tid == 0) cand_cnt = 0;

        // stage norms for this thread's columns
        float nrm_reg[WTILES];
        #pragma unroll
        for (int ct = 0; ct < WTILES; ++ct) nrm_reg[ct] = ns[wbase + ct * 16 + lrow];

        // ---- A fragments from residual (packed bf16 convert)
        bf16x8 afr[4][4];
        #pragma unroll
        for (int rt = 0; rt < 4; ++rt) {
            const float* rp = &res_row[rt * 16 + lrow][lkg * 8];
            #pragma unroll
            for (int kt = 0; kt < 4; ++kt) {
                float4 u = *reinterpret_cast<const float4*>(rp + kt * 32);
                float4 v = *reinterpret_cast<const float4*>(rp + kt * 32 + 4);
                u32x4 w;
                w[0] = cvt_pk_bf16(u.x, u.y); w[1] = cvt_pk_bf16(u.z, u.w);
                w[2] = cvt_pk_bf16(v.x, v.y); w[3] = cvt_pk_bf16(v.z, v.w);
                afr[rt][kt] = __builtin_bit_cast(bf16x8, w);
            }
        }

        float rmth[16];
        #pragma unroll
        for (int i = 0; i < 16; ++i) rmth[i] = 3.4e38f;

        // ---- pass 1: per-slot min only
        rvq_score_pass<0>(afr, nrm_reg, rmth, e16s, es, use16,
                          wbase, lrow, lkg, cand, &cand_cnt);

        // one butterfly at the end (16 col lanes -> wave row min)
        #pragma unroll
        for (int i = 0; i < 16; ++i) {
            float m = rmth[i];
            m = fminf(m, __shfl_xor(m, 1, 16));
            m = fminf(m, __shfl_xor(m, 2, 16));
            m = fminf(m, __shfl_xor(m, 4, 16));
            m = fminf(m, __shfl_xor(m, 8, 16));
            rmth[i] = m;
        }
        if (lrow == 0) {
            #pragma unroll
            for (int i = 0; i < 16; ++i)
                row_minw[wave][(i >> 2) * 16 + lkg * 4 + (i & 3)] = rmth[i];
        }
        __syncthreads();   // (1) row_minw + resets visible

        // thresholds = global row min over 8 waves + EPS
        #pragma unroll
        for (int i = 0; i < 16; ++i) {
            int row = (i >> 2) * 16 + lkg * 4 + (i & 3);
            float m = fminf(fminf(fminf(row_minw[0][row], row_minw[1][row]),
                                  fminf(row_minw[2][row], row_minw[3][row])),
                            fminf(fminf(row_minw[4][row], row_minw[5][row]),
                                  fminf(row_minw[6][row], row_minw[7][row])));
            rmth[i] = m + EPS;
        }

        // ---- pass 2: recompute scores, push rare candidates
        rvq_score_pass<1>(afr, nrm_reg, rmth, e16s, es, use16,
                          wbase, lrow, lkg, cand, &cand_cnt);
        __syncthreads();   // (2) cand ready

        // ---- exact f32 rescore; 4 independent FMA chains; lex (dist,idx) min
        int nc = cand_cnt; if (nc > CCAP) nc = CCAP;
        for (int i = tid; i < nc; i += 512) {
            unsigned e = cand[i];
            int row = (int)(e >> 10), col = (int)(e & (K - 1));
            const float*  rp = &res_row[row][0];
            const float4* ep = reinterpret_cast<const float4*>(es + (size_t)col * D);
            float d0 = 0.f, d1 = 0.f, d2 = 0.f, d3 = 0.f;
            #pragma unroll
            for (int q = 0; q < 8; ++q) {
                float4 rv0 = *reinterpret_cast<const float4*>(rp + q * 16);
                float4 rv1 = *reinterpret_cast<const float4*>(rp + q * 16 + 4);
                float4 rv2 = *reinterpret_cast<const float4*>(rp + q * 16 + 8);
                float4 rv3 = *reinterpret_cast<const float4*>(rp + q * 16 + 12);
                float4 e0 = ep[q * 4], e1 = ep[q * 4 + 1];
                float4 e2 = ep[q * 4 + 2], e3 = ep[q * 4 + 3];
                d0 = fmaf(rv0.x, e0.x, d0); d0 = fmaf(rv0.y, e0.y, d0);
                d0 = fmaf(rv0.z, e0.z, d0); d0 = fmaf(rv0.w, e0.w, d0);
                d1 = fmaf(rv1.x, e1.x, d1); d1 = fmaf(rv1.y, e1.y, d1);
                d1 = fmaf(rv1.z, e1.z, d1); d1 = fmaf(rv1.w, e1.w, d1);
                d2 = fmaf(rv2.x, e2.x, d2); d2 = fmaf(rv2.y, e2.y, d2);
                d2 = fmaf(rv2.z, e2.z, d2); d2 = fmaf(rv2.w, e2.w, d2);
                d3 = fmaf(rv3.x, e3.x, d3); d3 = fmaf(rv3.y, e3.y, d3);
                d3 = fmaf(rv3.z, e3.z, d3); d3 = fmaf(rv3.w, e3.w, d3);
            }
            float dot = (d0 + d1) + (d2 + d3);
            float dist = fmaf(-2.f, dot, ns[col]);
            unsigned du = __float_as_uint(dist);
            du ^= (du >> 31) ? 0xFFFFFFFFu : 0x80000000u;
            unsigned long long key = ((unsigned long long)du << 32) | (unsigned)col;
            atomicMin(&row_best[row], key);
        }
        __syncthreads();   // (3) row_best final

        // ---- index out + flags + residual update
        if (tid < BR) {
            int idx = (int)(row_best[tid] & (unsigned)(K - 1));
            out[ZQ_SIZE + ((size_t)b * NQ + s) * T + t0 + tid] = (float)idx;
            ws[WS_FLAGS + s * K + idx] = 1.0f;   // benign race
        }
        {
            const int row = tid >> 3;            // 0..63
            const int d0  = (tid & 7) * 16;      // 16 floats per thread
            const int idx = (int)(row_best[row] & (unsigned)(K - 1));
            const float* ev = es + (size_t)idx * D + d0;
            float* rr = &res_row[row][d0];
            #pragma unroll
            for (int p = 0; p < 4; ++p) {
                float4 e4 = *reinterpret_cast<const float4*>(ev + p * 4);
                float4 r4 = *reinterpret_cast<float4*>(rr + p * 4);
                float tx = e4.x - r4.x, zx = r4.x + tx;
                float ty = e4.y - r4.y, zy = r4.y + ty;
                float tz = e4.z - r4.z, zz = r4.z + tz;
                float tw = e4.w - r4.w, zw = r4.w + tw;
                float4 nr;
                nr.x = r4.x - zx; nr.y = r4.y - zy; nr.z = r4.z - zz; nr.w = r4.w - zw;
                commit_acc = fmaf(tx, tx, commit_acc);
                commit_acc = fmaf(ty, ty, commit_acc);
                commit_acc = fmaf(tz, tz, commit_acc);
                commit_acc = fmaf(tw, tw, commit_acc);
                *reinterpret_cast<float4*>(rr + p * 4) = nr;
            }
        }
        __syncthreads();   // (4) res_row stable, row_best reads done
    }

    // ---- z_q = z_e - final residual (telescoped sum of stage z_q_st)
    {
        const int r  = tid & 63;
        const int d0 = tid >> 6;
        for (int d = d0; d < D; d += 8) {
            size_t gi = ((size_t)b * D + d) * T + t0 + r;
            out[gi] = z_e[gi] - res_row[r][d];
        }
    }

    // ---- deterministic block reduction of commit partials
    cred[tid] = commit_acc;
    __syncthreads();
    for (int o = 256; o > 0; o >>= 1) {
        if (tid < o) cred[tid] += cred[tid + o];
        __syncthreads();
    }
    if (tid == 0) ws[WS_PARTIALS + blk] = cred[0];
}

__global__ void rvq_finalize_kernel(const float* __restrict__ ws,
                                    float* __restrict__ out) {
    __shared__ float sbuf[256];
    const int tid = threadIdx.x;

    float cs = 0.f;
    for (int i = tid; i < NBLK; i += 256) cs += ws[WS_PARTIALS + i];
    sbuf[tid] = cs;
    __syncthreads();
    for (int o = 128; o > 0; o >>= 1) {
        if (tid < o) sbuf[tid] += sbuf[tid + o];
        __syncthreads();
    }
    float commit = sbuf[0] / ((float)NQ * (float)N * (float)D);
    __syncthreads();

    float fs = 0.f;
    for (int i = tid; i < NQ * K; i += 256)
        fs += (ws[WS_FLAGS + i] != 0.f) ? 1.f : 0.f;
    sbuf[tid] = fs;
    __syncthreads();
    for (int o = 128; o > 0; o >>= 1) {
        if (tid < o) sbuf[tid] += sbuf[tid + o];
        __syncthreads();
    }
    if (tid == 0) {
        out[SCALAR_OFF + 0] = commit;
        out[SCALAR_OFF + 1] = sbuf[0] / (float)(NQ * K);
    }
}

extern "C" void kernel_launch(void* const* d_in, const int* in_sizes, int n_in,
                              void* d_out, int out_size, void* d_ws, size_t ws_size,
                              hipStream_t stream) {
    const float* z_e   = (const float*)d_in[0];
    const float* embed = (const float*)d_in[1];
    float* out = (float*)d_out;
    float* ws  = (float*)d_ws;

    int use16 = (ws_size >= WS_REQ_BYTES) ? 1 : 0;

    hipMemsetAsync(d_ws, 0, (NBLK + NQ * K) * sizeof(float), stream);
    rvq_norms_kernel<<<(NQ * K + 255) / 256, 256, 0, stream>>>(embed, ws + WS_NORMS);
    if (use16)
        rvq_emb16_kernel<<<(NQ * K * D / 8 + 255) / 256, 256, 0, stream>>>(
            embed, (unsigned short*)(ws + WS_EMB16_F));
    rvq_main_kernel<<<NBLK, 512, 0, stream>>>(
        z_e, embed, ws + WS_NORMS, (const unsigned short*)(ws + WS_EMB16_F),
        use16, out, ws);
    rvq_finalize_kernel<<<1, 256, 0, stream>>>(ws, out);
}